// Round 1
// 341.740 us; speedup vs baseline: 1.0227x; 1.0227x over previous
//
#include <hip/hip_runtime.h>

#define BATCH 16384
#define DIM 128
#define NLINK 500
#define NS 16            // sample slots per block round (16 groups x 32 lanes = 512 threads)
#define DP_STRIDE 132    // padded row stride in floats
#define CAP 128          // bucket capacity per link (Poisson mean 32.8; +16 sigma headroom)

// async global->LDS, 16B per lane; LDS dst must be wave-uniform base + lane*16 (it is:
// dst = Ms + (t + 512*i)*4 floats is linear in t).
__device__ __forceinline__ void gload_lds16(const float* g, float* l) {
    __builtin_amdgcn_global_load_lds(
        (const __attribute__((address_space(1))) void*)g,
        (__attribute__((address_space(3))) void*)l, 16, 0, 0);
}

__global__ void k_init(float* __restrict__ out) {
    if (threadIdx.x == 0) out[0] = 0.0f;
}

// One block per link. 512 threads = 16 groups (g = t>>5) x 32 lanes (q = t&31).
// Group handles sample slot g; lane q covers e-quad 4q..4q+3 of the full 128-e range.
__global__ __launch_bounds__(512, 2) void k_fused(
    const float* __restrict__ node_w, const float* __restrict__ link_w,
    const float* __restrict__ transfer_w,
    const int* __restrict__ sp, const int* __restrict__ tp,
    const int* __restrict__ sn, const int* __restrict__ tn,
    const int* __restrict__ r, float* __restrict__ out)
{
    __shared__ float Ms[DIM * DIM];        // 64 KB, full M row-major [d][e]
    __shared__ float dp[NS * DP_STRIDE];   // 8.25 KB, pos diffs (s-t), one row per group
    __shared__ float dn[NS * DP_STRIDE];   // 8.25 KB, neg diffs
    __shared__ float remb[DIM];            // 512 B
    __shared__ int   slist[CAP];           // sample indices for this link
    __shared__ int   cnt;
    __shared__ float lossbuf[NS];

    const int link = blockIdx.x;
    const int t = threadIdx.x;
    const int g = t >> 5;
    const int q = t & 31;

    if (t == 0) cnt = 0;
    __syncthreads();                       // nothing in flight yet: cheap

    // 1) r loads FIRST so the compact scan's wait leaves M staging in flight.
    int4 rv[8];
    #pragma unroll
    for (int j = 0; j < 8; j++) rv[j] = ((const int4*)r)[j * 512 + t];

    // 2) async-stage full 64 KB M into LDS (8 x 16B per thread, linear both sides).
    {
        const float* src = transfer_w + (size_t)link * (DIM * DIM);
        #pragma unroll
        for (int i = 0; i < 8; i++) {
            const int c = (t + 512 * i) * 4;   // float index
            gload_lds16(src + c, Ms + c);
        }
    }
    float4 rl;
    if (t < 32) rl = ((const float4*)(link_w + (size_t)link * DIM))[q];

    // 3) compact: my 32 candidates; ~33 hits per block total (LDS atomics, trivial).
    //    Runs while the M loads are still returning.
    #pragma unroll
    for (int j = 0; j < 8; j++) {
        const int bi = (j * 512 + t) * 4;
        if (rv[j].x == link) slist[atomicAdd(&cnt, 1)] = bi;
        if (rv[j].y == link) slist[atomicAdd(&cnt, 1)] = bi + 1;
        if (rv[j].z == link) slist[atomicAdd(&cnt, 1)] = bi + 2;
        if (rv[j].w == link) slist[atomicAdd(&cnt, 1)] = bi + 3;
    }
    if (t < 32) ((float4*)remb)[q] = rl;
    __syncthreads();   // drains vmcnt(0): Ms complete; slist/cnt/remb visible

    const int count = cnt;
    float* dpr = dp + g * DP_STRIDE;
    float* dnr = dn + g * DP_STRIDE;
    const float4* M4 = (const float4*)Ms;
    float groupSum = 0.0f;

    // Barrier-free round loop: group g's dp/dn row is touched only by the 32 lanes of
    // group g, and groups 2w,2w+1 live in wave w — all LDS deps are intra-wave, so the
    // compiler's lgkmcnt ordering suffices and the 8 waves drift/overlap freely.
    for (int k = 0; k < count; k += NS) {
        const bool active = (k + g < count);
        if (active) {
            const int b = slist[k + g];
            const float4* A = (const float4*)(node_w + (size_t)sp[b] * DIM);
            const float4* C = (const float4*)(node_w + (size_t)tp[b] * DIM);
            float4 a0 = A[q], c0 = C[q];
            float4 w;
            w.x = a0.x - c0.x; w.y = a0.y - c0.y; w.z = a0.z - c0.z; w.w = a0.w - c0.w;
            ((float4*)dpr)[q] = w;
            const float4* E = (const float4*)(node_w + (size_t)sn[b] * DIM);
            const float4* F = (const float4*)(node_w + (size_t)tn[b] * DIM);
            float4 e0 = E[q], f0 = F[q];
            w.x = e0.x - f0.x; w.y = e0.y - f0.y; w.z = e0.z - f0.z; w.w = e0.w - f0.w;
            ((float4*)dnr)[q] = w;
        }

        float4 accp = {0.f, 0.f, 0.f, 0.f};
        float4 accn = {0.f, 0.f, 0.f, 0.f};
        #pragma unroll 4
        for (int d4 = 0; d4 < 32; d4++) {
            float4 vp = ((const float4*)dpr)[d4];   // 32-lane broadcast
            float4 vn = ((const float4*)dnr)[d4];
            float4 m0 = M4[(4 * d4 + 0) * 32 + q];  // 512B contiguous per group,
            float4 m1 = M4[(4 * d4 + 1) * 32 + q];  // duplicated across half-waves -> bcast
            float4 m2 = M4[(4 * d4 + 2) * 32 + q];
            float4 m3 = M4[(4 * d4 + 3) * 32 + q];
            accp.x = fmaf(m0.x, vp.x, accp.x); accp.y = fmaf(m0.y, vp.x, accp.y);
            accp.z = fmaf(m0.z, vp.x, accp.z); accp.w = fmaf(m0.w, vp.x, accp.w);
            accn.x = fmaf(m0.x, vn.x, accn.x); accn.y = fmaf(m0.y, vn.x, accn.y);
            accn.z = fmaf(m0.z, vn.x, accn.z); accn.w = fmaf(m0.w, vn.x, accn.w);
            accp.x = fmaf(m1.x, vp.y, accp.x); accp.y = fmaf(m1.y, vp.y, accp.y);
            accp.z = fmaf(m1.z, vp.y, accp.z); accp.w = fmaf(m1.w, vp.y, accp.w);
            accn.x = fmaf(m1.x, vn.y, accn.x); accn.y = fmaf(m1.y, vn.y, accn.y);
            accn.z = fmaf(m1.z, vn.y, accn.z); accn.w = fmaf(m1.w, vn.y, accn.w);
            accp.x = fmaf(m2.x, vp.z, accp.x); accp.y = fmaf(m2.y, vp.z, accp.y);
            accp.z = fmaf(m2.z, vp.z, accp.z); accp.w = fmaf(m2.w, vp.z, accp.w);
            accn.x = fmaf(m2.x, vn.z, accn.x); accn.y = fmaf(m2.y, vn.z, accn.y);
            accn.z = fmaf(m2.z, vn.z, accn.z); accn.w = fmaf(m2.w, vn.z, accn.w);
            accp.x = fmaf(m3.x, vp.w, accp.x); accp.y = fmaf(m3.y, vp.w, accp.y);
            accp.z = fmaf(m3.z, vp.w, accp.z); accp.w = fmaf(m3.w, vp.w, accp.w);
            accn.x = fmaf(m3.x, vn.w, accn.x); accn.y = fmaf(m3.y, vn.w, accn.y);
            accn.z = fmaf(m3.z, vn.w, accn.z); accn.w = fmaf(m3.w, vn.w, accn.w);
        }

        float4 re = ((const float4*)remb)[q];
        float v = fabsf(accp.x + re.x) + fabsf(accp.y + re.y)
                + fabsf(accp.z + re.z) + fabsf(accp.w + re.w)
                - fabsf(accn.x + re.x) - fabsf(accn.y + re.y)
                - fabsf(accn.z + re.z) - fabsf(accn.w + re.w);
        // v = pos_partial - neg_partial over e = 4q..4q+3; reduce over the 32-lane group
        #pragma unroll
        for (int o = 16; o >= 1; o >>= 1) v += __shfl_xor(v, o, 32);
        if (active && q == 0) groupSum += fmaxf(v + 1.0f, 0.0f);
    }

    if (q == 0) lossbuf[g] = groupSum;     // all 16 groups write (0 if never active)
    __syncthreads();                       // waves exit the loop at different times
    if (t == 0) {
        float s = 0.0f;
        #pragma unroll
        for (int i = 0; i < NS; i++) s += lossbuf[i];
        atomicAdd(out, s * (1.0f / BATCH));
    }
}

extern "C" void kernel_launch(void* const* d_in, const int* in_sizes, int n_in,
                              void* d_out, int out_size, void* d_ws, size_t ws_size,
                              hipStream_t stream) {
    const float* node_w     = (const float*)d_in[0];
    const float* link_w     = (const float*)d_in[1];
    const float* transfer_w = (const float*)d_in[2];
    const int* sp = (const int*)d_in[3];
    const int* tp = (const int*)d_in[4];
    const int* sn = (const int*)d_in[5];
    const int* tn = (const int*)d_in[6];
    const int* r  = (const int*)d_in[7];
    float* out = (float*)d_out;
    (void)d_ws; (void)ws_size;   // workspace no longer needed

    k_init<<<1, 64, 0, stream>>>(out);
    k_fused<<<NLINK, 512, 0, stream>>>(node_w, link_w, transfer_w,
                                       sp, tp, sn, tn, r, out);
}

// Round 2
// 339.013 us; speedup vs baseline: 1.0309x; 1.0080x over previous
//
#include <hip/hip_runtime.h>

#define BATCH 16384
#define DIM 128
#define NLINK 500
#define NS 16            // groups per block (32 lanes each); slots strided by NS
#define DP_STRIDE 132    // padded row stride in floats
#define CAP 128          // bucket capacity per link (Poisson mean 32.8)

// async global->LDS, 16B per lane; LDS dst is wave-uniform base + lane*16 (linear in t).
__device__ __forceinline__ void gload_lds16(const float* g, float* l) {
    __builtin_amdgcn_global_load_lds(
        (const __attribute__((address_space(1))) void*)g,
        (__attribute__((address_space(3))) void*)l, 16, 0, 0);
}

__global__ void k_init(float* __restrict__ out) {
    if (threadIdx.x == 0) out[0] = 0.0f;
}

#define FMA4(acc, m, s)                                          \
    acc.x = fmaf(m.x, s, acc.x); acc.y = fmaf(m.y, s, acc.y);    \
    acc.z = fmaf(m.z, s, acc.z); acc.w = fmaf(m.w, s, acc.w);

// One block per link. 512 threads = 16 groups (g = t>>5) x 32 lanes (q = t&31).
// Group g privately processes slots {g, g+16, g+32, ...} in PAIRS (myk, myk+16):
// one 64 KB M sweep feeds 4 accumulators (p/n x 2 samples) -> M ds_reads halve
// per sample. Barrier-free: each group's dp/dn rows are touched only by its own
// 32 lanes (intra-wave ordering via lgkmcnt), so waves drift and exit early.
__global__ __launch_bounds__(512, 2) void k_fused(
    const float* __restrict__ node_w, const float* __restrict__ link_w,
    const float* __restrict__ transfer_w,
    const int* __restrict__ sp, const int* __restrict__ tp,
    const int* __restrict__ sn, const int* __restrict__ tn,
    const int* __restrict__ r, float* __restrict__ out)
{
    __shared__ float Ms[DIM * DIM];          // 64 KB, full M row-major [d][e]
    __shared__ float dp0[NS * DP_STRIDE];    // pos diffs, sample 0 of pair
    __shared__ float dn0[NS * DP_STRIDE];    // neg diffs, sample 0
    __shared__ float dp1[NS * DP_STRIDE];    // pos diffs, sample 1
    __shared__ float dn1[NS * DP_STRIDE];    // neg diffs, sample 1  (4 x 8.25 KB)
    __shared__ float remb[DIM];              // 512 B
    __shared__ int   slist[CAP];
    __shared__ int   cnt;
    __shared__ float lossbuf[NS];
    // total ~98 KB -> 1 block/CU (which the 81 KB version already was)

    const int link = blockIdx.x;
    const int t = threadIdx.x;
    const int g = t >> 5;
    const int q = t & 31;

    if (t == 0) cnt = 0;
    __syncthreads();

    // r loads first so the compact scan's wait leaves M staging in flight.
    int4 rv[8];
    #pragma unroll
    for (int j = 0; j < 8; j++) rv[j] = ((const int4*)r)[j * 512 + t];

    // async-stage full 64 KB M into LDS (8 x 16B per thread, linear both sides).
    {
        const float* src = transfer_w + (size_t)link * (DIM * DIM);
        #pragma unroll
        for (int i = 0; i < 8; i++) {
            const int c = (t + 512 * i) * 4;
            gload_lds16(src + c, Ms + c);
        }
    }
    float4 rl;
    if (t < 32) rl = ((const float4*)(link_w + (size_t)link * DIM))[q];

    #pragma unroll
    for (int j = 0; j < 8; j++) {
        const int bi = (j * 512 + t) * 4;
        if (rv[j].x == link) slist[atomicAdd(&cnt, 1)] = bi;
        if (rv[j].y == link) slist[atomicAdd(&cnt, 1)] = bi + 1;
        if (rv[j].z == link) slist[atomicAdd(&cnt, 1)] = bi + 2;
        if (rv[j].w == link) slist[atomicAdd(&cnt, 1)] = bi + 3;
    }
    if (t < 32) ((float4*)remb)[q] = rl;
    __syncthreads();   // drains vmcnt(0): Ms complete; slist/cnt/remb visible

    const int count = cnt;
    float* p0r = dp0 + g * DP_STRIDE;
    float* n0r = dn0 + g * DP_STRIDE;
    float* p1r = dp1 + g * DP_STRIDE;
    float* n1r = dn1 + g * DP_STRIDE;
    const float4* M4 = (const float4*)Ms;
    float groupSum = 0.0f;

    int myk = g;
    if (myk < count) {                      // stage first pair
        const int b0 = slist[myk];
        const int b1 = (myk + 16 < count) ? slist[myk + 16] : b0;  // pad = dup
        float4 a0 = ((const float4*)(node_w + (size_t)sp[b0] * DIM))[q];
        float4 c0 = ((const float4*)(node_w + (size_t)tp[b0] * DIM))[q];
        float4 e0 = ((const float4*)(node_w + (size_t)sn[b0] * DIM))[q];
        float4 f0 = ((const float4*)(node_w + (size_t)tn[b0] * DIM))[q];
        float4 a1 = ((const float4*)(node_w + (size_t)sp[b1] * DIM))[q];
        float4 c1 = ((const float4*)(node_w + (size_t)tp[b1] * DIM))[q];
        float4 e1 = ((const float4*)(node_w + (size_t)sn[b1] * DIM))[q];
        float4 f1 = ((const float4*)(node_w + (size_t)tn[b1] * DIM))[q];
        float4 w;
        w.x = a0.x - c0.x; w.y = a0.y - c0.y; w.z = a0.z - c0.z; w.w = a0.w - c0.w;
        ((float4*)p0r)[q] = w;
        w.x = e0.x - f0.x; w.y = e0.y - f0.y; w.z = e0.z - f0.z; w.w = e0.w - f0.w;
        ((float4*)n0r)[q] = w;
        w.x = a1.x - c1.x; w.y = a1.y - c1.y; w.z = a1.z - c1.z; w.w = a1.w - c1.w;
        ((float4*)p1r)[q] = w;
        w.x = e1.x - f1.x; w.y = e1.y - f1.y; w.z = e1.z - f1.z; w.w = e1.w - f1.w;
        ((float4*)n1r)[q] = w;
    }

    while (myk < count) {
        const bool act1 = (myk + 16) < count;
        const int nk = myk + 32;
        const bool hn = nk < count;
        // prefetch next pair's 8 rows into registers; consumed after the sweep
        float4 pa0, pc0, pe0, pf0, pa1, pc1, pe1, pf1;
        if (hn) {
            const int nb0 = slist[nk];
            const int nb1 = (nk + 16 < count) ? slist[nk + 16] : nb0;
            pa0 = ((const float4*)(node_w + (size_t)sp[nb0] * DIM))[q];
            pc0 = ((const float4*)(node_w + (size_t)tp[nb0] * DIM))[q];
            pe0 = ((const float4*)(node_w + (size_t)sn[nb0] * DIM))[q];
            pf0 = ((const float4*)(node_w + (size_t)tn[nb0] * DIM))[q];
            pa1 = ((const float4*)(node_w + (size_t)sp[nb1] * DIM))[q];
            pc1 = ((const float4*)(node_w + (size_t)tp[nb1] * DIM))[q];
            pe1 = ((const float4*)(node_w + (size_t)sn[nb1] * DIM))[q];
            pf1 = ((const float4*)(node_w + (size_t)tn[nb1] * DIM))[q];
        }

        float4 ap0 = {0.f,0.f,0.f,0.f}, an0 = {0.f,0.f,0.f,0.f};
        float4 ap1 = {0.f,0.f,0.f,0.f}, an1 = {0.f,0.f,0.f,0.f};
        #pragma unroll 4
        for (int d4 = 0; d4 < 32; d4++) {
            float4 vp0 = ((const float4*)p0r)[d4];   // 32-lane broadcasts
            float4 vn0 = ((const float4*)n0r)[d4];
            float4 vp1 = ((const float4*)p1r)[d4];
            float4 vn1 = ((const float4*)n1r)[d4];
            float4 m0 = M4[(4 * d4 + 0) * 32 + q];   // one M sweep, 4 matvecs
            float4 m1 = M4[(4 * d4 + 1) * 32 + q];
            float4 m2 = M4[(4 * d4 + 2) * 32 + q];
            float4 m3 = M4[(4 * d4 + 3) * 32 + q];
            FMA4(ap0, m0, vp0.x) FMA4(an0, m0, vn0.x)
            FMA4(ap1, m0, vp1.x) FMA4(an1, m0, vn1.x)
            FMA4(ap0, m1, vp0.y) FMA4(an0, m1, vn0.y)
            FMA4(ap1, m1, vp1.y) FMA4(an1, m1, vn1.y)
            FMA4(ap0, m2, vp0.z) FMA4(an0, m2, vn0.z)
            FMA4(ap1, m2, vp1.z) FMA4(an1, m2, vn1.z)
            FMA4(ap0, m3, vp0.w) FMA4(an0, m3, vn0.w)
            FMA4(ap1, m3, vp1.w) FMA4(an1, m3, vn1.w)
        }

        float4 re = ((const float4*)remb)[q];
        float v0 = fabsf(ap0.x + re.x) + fabsf(ap0.y + re.y)
                 + fabsf(ap0.z + re.z) + fabsf(ap0.w + re.w)
                 - fabsf(an0.x + re.x) - fabsf(an0.y + re.y)
                 - fabsf(an0.z + re.z) - fabsf(an0.w + re.w);
        float v1 = fabsf(ap1.x + re.x) + fabsf(ap1.y + re.y)
                 + fabsf(ap1.z + re.z) + fabsf(ap1.w + re.w)
                 - fabsf(an1.x + re.x) - fabsf(an1.y + re.y)
                 - fabsf(an1.z + re.z) - fabsf(an1.w + re.w);
        #pragma unroll
        for (int o = 16; o >= 1; o >>= 1) {
            v0 += __shfl_xor(v0, o, 32);
            v1 += __shfl_xor(v1, o, 32);
        }
        if (q == 0) {
            groupSum += fmaxf(v0 + 1.0f, 0.0f);
            if (act1) groupSum += fmaxf(v1 + 1.0f, 0.0f);
        }

        if (hn) {   // WAR safe: same-wave DS ops execute in order
            float4 w;
            w.x = pa0.x - pc0.x; w.y = pa0.y - pc0.y; w.z = pa0.z - pc0.z; w.w = pa0.w - pc0.w;
            ((float4*)p0r)[q] = w;
            w.x = pe0.x - pf0.x; w.y = pe0.y - pf0.y; w.z = pe0.z - pf0.z; w.w = pe0.w - pf0.w;
            ((float4*)n0r)[q] = w;
            w.x = pa1.x - pc1.x; w.y = pa1.y - pc1.y; w.z = pa1.z - pc1.z; w.w = pa1.w - pc1.w;
            ((float4*)p1r)[q] = w;
            w.x = pe1.x - pf1.x; w.y = pe1.y - pf1.y; w.z = pe1.z - pf1.z; w.w = pe1.w - pf1.w;
            ((float4*)n1r)[q] = w;
        }
        myk = nk;
    }

    if (q == 0) lossbuf[g] = groupSum;
    __syncthreads();
    if (t == 0) {
        float s = 0.0f;
        #pragma unroll
        for (int i = 0; i < NS; i++) s += lossbuf[i];
        atomicAdd(out, s * (1.0f / BATCH));
    }
}

extern "C" void kernel_launch(void* const* d_in, const int* in_sizes, int n_in,
                              void* d_out, int out_size, void* d_ws, size_t ws_size,
                              hipStream_t stream) {
    const float* node_w     = (const float*)d_in[0];
    const float* link_w     = (const float*)d_in[1];
    const float* transfer_w = (const float*)d_in[2];
    const int* sp = (const int*)d_in[3];
    const int* tp = (const int*)d_in[4];
    const int* sn = (const int*)d_in[5];
    const int* tn = (const int*)d_in[6];
    const int* r  = (const int*)d_in[7];
    float* out = (float*)d_out;
    (void)d_ws; (void)ws_size;

    k_init<<<1, 64, 0, stream>>>(out);
    k_fused<<<NLINK, 512, 0, stream>>>(node_w, link_w, transfer_w,
                                       sp, tp, sn, tn, r, out);
}